// Round 1
// 789.503 us; speedup vs baseline: 1.0595x; 1.0595x over previous
//
#include <hip/hip_runtime.h>

#define T_STEPS 256
#define B_SZ    128
#define F_SZ    2500
#define F4      625        // F_SZ / 4
#define F_P     2528       // padded K for bf16 W1 arrays: 79*32; row = 5056 B (16B aligned)
#define NSTEP   79         // F_P / 32
#define H_SZ    128
#define O_SZ    2
#define FLAG_WINDOW 8e-5   // |mem-1| < window => fp64 recheck (bf16x4-split cur1 err RMS ~3e-6)
#define CHUNK   12         // flagged W1 rows staged in LDS per pass (120 KB)

typedef unsigned short U16;
typedef short  s16x8 __attribute__((ext_vector_type(8)));
typedef U16    u16x8 __attribute__((ext_vector_type(8)));
typedef float  f32x4 __attribute__((ext_vector_type(4)));

__device__ __forceinline__ U16 bf16_rne(float f) {
    unsigned u = __float_as_uint(f);
    u += 0x7FFFu + ((u >> 16) & 1u);
    return (U16)(u >> 16);
}

// ---------------- K1: split W1 [H][F] -> bf16 hi/lo [H][F_P] (zero-padded); zero flag counts ----------------
// hi = rne_bf16(w); lo = rne_bf16(w - hi): w represented to ~2^-18 relative.
__global__ __launch_bounds__(256) void k_split(const float* __restrict__ W1,
                                               U16* __restrict__ W1h,
                                               U16* __restrict__ W1l,
                                               int* __restrict__ nh) {
    const int h = blockIdx.x;                           // 128 blocks
    if (h == 0 && threadIdx.x < B_SZ) nh[threadIdx.x] = 0;
    for (int k = threadIdx.x; k < F_P; k += 256) {
        const float w = (k < F_SZ) ? W1[(size_t)h * F_SZ + k] : 0.f;
        const U16 hi = bf16_rne(w);
        const float hf = __uint_as_float((unsigned)hi << 16);
        W1h[(size_t)h * F_P + k] = hi;
        W1l[(size_t)h * F_P + k] = bf16_rne(w - hf);
    }
}

// ---------------- K2: cur1[t][b][h] = x[b][t][:] . W1[h][:]  via bf16 split MFMA ----------------
// fp32 emulation: acc += hh + hl + lh + ll on mfma_f32_16x16x32_bf16 (fp32 accumulate).
// Tile 128(b) x 64(h), BK=32, grid 512 (t = bid>>1, h-half = bid&1), 2 blocks/CU (48 KB LDS).
// LDS rows = 128 B: [32 hi bf16 | 32 lo bf16], 16B units XOR-swizzled by (row&7) ->
// staging writes and frag reads are both <=2-way (free). Frag layout (m92/m89 verified):
// A/B frag: row = lane&15, k = (lane>>4)*8 + i (8 contiguous); C/D: col=lane&15, row=(lane>>4)*4+reg.
__global__ __launch_bounds__(256, 2) void k_gemm(const float* __restrict__ x,
                                                 const U16* __restrict__ W1h,
                                                 const U16* __restrict__ W1l,
                                                 float* __restrict__ cur1) {
    __shared__ __align__(16) U16 Alds[2][128 * 64];   // 2 x 16 KB
    __shared__ __align__(16) U16 Blds[2][64 * 64];    // 2 x  8 KB

    const int tid = threadIdx.x;
    const int t   = blockIdx.x >> 1;
    const int h0  = (blockIdx.x & 1) << 6;

    // ---- A staging map: thread -> (row ra, 16 k starting at kq) ----
    const int ra   = tid >> 1;                 // b-row 0..127
    const int kq   = (tid & 1) << 4;           // 0 | 16
    const int aswz = ra & 7;
    const int au0  = (tid & 1) << 1;           // logical hi units au0, au0+1
    const float* xp = x + ((size_t)ra * T_STEPS + t) * F_SZ + kq;

    // ---- B staging map: thread -> (row rb, storage units ub0, ub0+1) ----
    // storage unit u holds logical unit u^(rb&7); source pointers are loop-invariant.
    const int rb  = tid >> 2;                  // h-row 0..63
    const int ub0 = (tid & 3) << 1;
    const U16* bsrc[2];
    #pragma unroll
    for (int c = 0; c < 2; ++c) {
        const int lu = (ub0 + c) ^ (rb & 7);
        const U16* base = (lu < 4) ? (W1h + lu * 8) : (W1l + (lu - 4) * 8);
        bsrc[c] = base + (size_t)(h0 + rb) * F_P;
    }

    // ---- wave / fragment map ----
    const int wid = tid >> 6, lane = tid & 63;
    const int wm0 = (wid >> 1) << 6;           // 0 | 64  (b)
    const int wn0 = (wid & 1) << 5;            // 0 | 32  (h)
    const int lr = lane & 15, lg = lane >> 4;

    f32x4 acc[4][2];
    #pragma unroll
    for (int i = 0; i < 4; ++i)
        #pragma unroll
        for (int j = 0; j < 2; ++j) {
            acc[i][j][0] = 0.f; acc[i][j][1] = 0.f; acc[i][j][2] = 0.f; acc[i][j][3] = 0.f;
        }

    float4 xr[4];
    u16x8  br[2];

    auto loadX = [&](int kk) {
        #pragma unroll
        for (int c = 0; c < 4; ++c) {
            const int k = kk + kq + c * 4;
            xr[c] = (k < F_SZ) ? *(const float4*)(xp + kk + c * 4)
                               : make_float4(0.f, 0.f, 0.f, 0.f);
        }
    };
    auto loadB = [&](int kk) {
        #pragma unroll
        for (int c = 0; c < 2; ++c) br[c] = *(const u16x8*)(bsrc[c] + kk);
    };
    auto stage = [&](int bb) {
        U16* Ab = Alds[bb];
        U16* Bb = Blds[bb];
        u16x8 vh[2], vl[2];
        #pragma unroll
        for (int p = 0; p < 2; ++p) {
            const float* f0 = (const float*)&xr[p * 2];
            const float* f1 = (const float*)&xr[p * 2 + 1];
            #pragma unroll
            for (int j = 0; j < 4; ++j) {
                const float v0 = f0[j], v1 = f1[j];
                const U16 hv0 = bf16_rne(v0);
                const U16 hv1 = bf16_rne(v1);
                vh[p][j]     = hv0;
                vh[p][4 + j] = hv1;
                vl[p][j]     = bf16_rne(v0 - __uint_as_float((unsigned)hv0 << 16));
                vl[p][4 + j] = bf16_rne(v1 - __uint_as_float((unsigned)hv1 << 16));
            }
        }
        #pragma unroll
        for (int p = 0; p < 2; ++p) {
            *(u16x8*)(Ab + ra * 64 + (((au0 + p) ^ aswz) << 3))       = vh[p];
            *(u16x8*)(Ab + ra * 64 + (((au0 + p + 4) ^ aswz) << 3))   = vl[p];
        }
        #pragma unroll
        for (int c = 0; c < 2; ++c)
            *(u16x8*)(Bb + rb * 64 + ((ub0 + c) << 3)) = br[c];
    };

    // prologue: fill buffer 0
    loadX(0);
    loadB(0);
    stage(0);

    int bb = 0;
    #pragma unroll 1
    for (int s = 0; s < NSTEP; ++s) {
        __syncthreads();                       // buf bb ready; buf bb^1 free
        const bool more = (s + 1 < NSTEP);
        if (more) { loadX((s + 1) * 32); loadB((s + 1) * 32); }   // in flight under MFMAs

        const U16* Ab = Alds[bb];
        const U16* Bb = Blds[bb];
        s16x8 ah[4], al[4], bh[2], blo[2];
        #pragma unroll
        for (int fi = 0; fi < 4; ++fi) {
            const int m = wm0 + fi * 16 + lr;
            const int msw = m & 7;
            ah[fi] = *(const s16x8*)(Ab + m * 64 + ((lg ^ msw) << 3));
            al[fi] = *(const s16x8*)(Ab + m * 64 + (((lg + 4) ^ msw) << 3));
        }
        #pragma unroll
        for (int fj = 0; fj < 2; ++fj) {
            const int n = wn0 + fj * 16 + lr;
            const int nsw = n & 7;
            bh[fj]  = *(const s16x8*)(Bb + n * 64 + ((lg ^ nsw) << 3));
            blo[fj] = *(const s16x8*)(Bb + n * 64 + (((lg + 4) ^ nsw) << 3));
        }
        #pragma unroll
        for (int fi = 0; fi < 4; ++fi)
            #pragma unroll
            for (int fj = 0; fj < 2; ++fj) {
                acc[fi][fj] = __builtin_amdgcn_mfma_f32_16x16x32_bf16(ah[fi], bh[fj],  acc[fi][fj], 0, 0, 0);
                acc[fi][fj] = __builtin_amdgcn_mfma_f32_16x16x32_bf16(ah[fi], blo[fj], acc[fi][fj], 0, 0, 0);
                acc[fi][fj] = __builtin_amdgcn_mfma_f32_16x16x32_bf16(al[fi], bh[fj],  acc[fi][fj], 0, 0, 0);
                acc[fi][fj] = __builtin_amdgcn_mfma_f32_16x16x32_bf16(al[fi], blo[fj], acc[fi][fj], 0, 0, 0);
            }

        if (more) stage(bb ^ 1);               // next tile into the other buffer
        bb ^= 1;
    }

    // epilogue: C/D layout col=lane&15, row=(lane>>4)*4+reg
    #pragma unroll
    for (int fi = 0; fi < 4; ++fi)
        #pragma unroll
        for (int fj = 0; fj < 2; ++fj) {
            const int hcol = h0 + wn0 + fj * 16 + lr;
            #pragma unroll
            for (int r = 0; r < 4; ++r) {
                const int brow = wm0 + fi * 16 + lg * 4 + r;
                cur1[((size_t)t * B_SZ + brow) * H_SZ + hcol] = acc[fi][fj][r];
            }
        }
}

// ---------------- K3: LIF1 (fp64 chain on fp32 dots + bias), spikes -> ballot bitmasks ----------------
// Thread per (b,h); block = 2 b x 128 h; wave = 64 h of one b. Flags near-threshold neurons.
__global__ __launch_bounds__(256) void k_lif1(const float* __restrict__ cur1,
                                              const float* __restrict__ b1,
                                              unsigned long long* __restrict__ spk_bits,
                                              int* __restrict__ nh,
                                              int* __restrict__ hlist) {
    const int idx = blockIdx.x * 256 + threadIdx.x;   // b*128+h
    const int b = idx >> 7, h = idx & 127;
    const double b1v = (double)b1[h];
    double mem = 0.0;
    bool flagged = false;
    #pragma unroll 4                                   // overlap the address-independent loads
    for (int t = 0; t < T_STEPS; ++t) {
        const double cur = (double)cur1[(size_t)t * 16384 + idx] + b1v;
        const double rst = (mem > 1.0) ? 1.0 : 0.0;
        mem = fma(0.9, mem, cur) - rst;               // EXACT form replicated in k_fixB
        const bool spk = (mem > 1.0);
        const unsigned long long m = __ballot(spk);
        if ((threadIdx.x & 63) == 0)
            spk_bits[((size_t)t * B_SZ + b) * 2 + ((h >> 6) & 1)] = m;
        if (!flagged && fabs(mem - 1.0) < FLAG_WINDOW) {
            flagged = true;
            int s = atomicAdd(&nh[b], 1);             // s < 128 structurally
            hlist[b * 128 + s] = h;
        }
    }
}

// ---------------- K4: cur2[t][b][o] = sum_{h set} W2[o][h] + b2[o] (fp64, from bitmasks) ----------------
__global__ __launch_bounds__(256) void k_cur2(const unsigned long long* __restrict__ bits,
                                              const float* __restrict__ W2,
                                              const float* __restrict__ b2,
                                              double* __restrict__ cur2) {
    __shared__ float w2s[256];
    w2s[threadIdx.x] = W2[threadIdx.x];
    __syncthreads();
    const int pair = blockIdx.x * 256 + threadIdx.x;  // t*128+b, grid 128 blocks
    unsigned long long m0 = bits[(size_t)pair * 2];
    unsigned long long m1 = bits[(size_t)pair * 2 + 1];
    double v0 = (double)b2[0], v1 = (double)b2[1];
    while (m0) {
        const int i = __ffsll((long long)m0) - 1; m0 &= m0 - 1;
        v0 += (double)w2s[i]; v1 += (double)w2s[128 + i];
    }
    while (m1) {
        const int i = __ffsll((long long)m1) - 1; m1 &= m1 - 1;
        v0 += (double)w2s[64 + i]; v1 += (double)w2s[192 + i];
    }
    cur2[(size_t)pair * 2]     = v0;
    cur2[(size_t)pair * 2 + 1] = v1;
}

// ---------------- K5a: exact fp64 dots for flagged neurons ----------------
__global__ __launch_bounds__(256) void k_fixA(const float* __restrict__ x,
                                              const float* __restrict__ W1,
                                              const int* __restrict__ nh,
                                              const int* __restrict__ hlist,
                                              double* __restrict__ cur_fix) {
    const int b   = blockIdx.x >> 4;
    const int tch = blockIdx.x & 15;
    const int n   = nh[b];
    if (n == 0) return;

    __shared__ float w1s[CHUNK * F_SZ];   // 120 KB
    const int tid  = threadIdx.x;
    const int wv   = tid >> 6;
    const int lane = tid & 63;

    for (int c0 = 0; c0 < n; c0 += CHUNK) {
        const int nc = (n - c0 < CHUNK) ? (n - c0) : CHUNK;
        __syncthreads();
        for (int r = 0; r < nc; ++r) {
            const int h = hlist[b * 128 + c0 + r];
            const float4* src = (const float4*)W1 + (size_t)h * F4;
            float4* dst = (float4*)(w1s + r * F_SZ);
            for (int c = tid; c < F4; c += 256) dst[c] = src[c];
        }
        __syncthreads();

        #pragma unroll 1
        for (int tt = 0; tt < 4; ++tt) {
            const int t = tch * 16 + wv * 4 + tt;
            float4 xv[10];
            const float4* xb = (const float4*)x + ((size_t)b * T_STEPS + t) * F4;
            #pragma unroll
            for (int j = 0; j < 10; ++j) {
                const int c = lane + 64 * j;
                xv[j] = (c < F4) ? xb[c] : make_float4(0.f, 0.f, 0.f, 0.f);
            }
            for (int s = 0; s < nc; ++s) {
                const float* wr = w1s + s * F_SZ;
                double p = 0.0;
                #pragma unroll
                for (int j = 0; j < 10; ++j) {
                    const int c = lane + 64 * j;
                    if (c < F4) {
                        const float4 w4 = *(const float4*)(wr + c * 4);
                        p = fma((double)xv[j].x, (double)w4.x, p);
                        p = fma((double)xv[j].y, (double)w4.y, p);
                        p = fma((double)xv[j].z, (double)w4.z, p);
                        p = fma((double)xv[j].w, (double)w4.w, p);
                    }
                }
                #pragma unroll
                for (int off = 32; off >= 1; off >>= 1) p += __shfl_down(p, off);
                if (lane == 0)
                    cur_fix[((size_t)b * 128 + c0 + s) * T_STEPS + t] = p;
            }
        }
    }
}

// ---------------- K5b: rerun approx+exact chains for flags; patch cur2 where spikes differ ----------------
__global__ __launch_bounds__(128) void k_fixB(const float* __restrict__ cur1,
                                              const double* __restrict__ cur_fix,
                                              const float* __restrict__ b1,
                                              const float* __restrict__ W2,
                                              const int* __restrict__ nh,
                                              const int* __restrict__ hlist,
                                              double* __restrict__ cur2) {
    const int b = blockIdx.x;        // 128
    const int s = threadIdx.x;       // 128
    if (s >= nh[b]) return;
    const int h = hlist[b * 128 + s];
    const double b1v = (double)b1[h];
    const double w0 = (double)W2[h], w1 = (double)W2[128 + h];
    double ma = 0.0, me = 0.0;
    for (int t = 0; t < T_STEPS; ++t) {
        const double ca = (double)cur1[((size_t)t * B_SZ + b) * H_SZ + h] + b1v;
        const double ce = cur_fix[((size_t)b * 128 + s) * T_STEPS + t] + b1v;
        const double ra = (ma > 1.0) ? 1.0 : 0.0;
        const double re = (me > 1.0) ? 1.0 : 0.0;
        ma = fma(0.9, ma, ca) - ra;   // bit-identical to k_lif1
        me = fma(0.9, me, ce) - re;
        const bool sa = (ma > 1.0), se = (me > 1.0);
        if (sa != se) {
            const double d = se ? 1.0 : -1.0;
            atomicAdd(&cur2[((size_t)t * B_SZ + b) * 2 + 0], d * w0);
            atomicAdd(&cur2[((size_t)t * B_SZ + b) * 2 + 1], d * w1);
        }
    }
}

// ---------------- K6: LIF2 (fp64) + fp32 outputs ----------------
__global__ __launch_bounds__(256) void k_lif2(const double* __restrict__ cur2,
                                              float* __restrict__ out) {
    const int tid = threadIdx.x;     // b*2+o
    double mem = 0.0;
    float* spk_out = out;
    float* mem_out = out + T_STEPS * B_SZ * O_SZ;
    #pragma unroll 8
    for (int t = 0; t < T_STEPS; ++t) {
        const double cur = cur2[t * 256 + tid];
        const double rst = (mem > 1.0) ? 1.0 : 0.0;
        mem = fma(0.9, mem, cur) - rst;
        spk_out[t * 256 + tid] = (mem > 1.0) ? 1.0f : 0.0f;
        mem_out[t * 256 + tid] = (float)mem;
    }
}

extern "C" void kernel_launch(void* const* d_in, const int* in_sizes, int n_in,
                              void* d_out, int out_size, void* d_ws, size_t ws_size,
                              hipStream_t stream) {
    const float* x  = (const float*)d_in[0];   // [128][256][2500]
    const float* W1 = (const float*)d_in[1];   // [128][2500]
    const float* b1 = (const float*)d_in[2];   // [128]
    const float* W2 = (const float*)d_in[3];   // [2][128]
    const float* b2 = (const float*)d_in[4];   // [2]
    float* out = (float*)d_out;                // 131072 floats

    char* ws = (char*)d_ws;
    float*  cur1    = (float*)ws;                           // 16,777,216 B
    U16*    W1h     = (U16*)(ws + 16777216);                //    647,168 B
    U16*    W1l     = (U16*)(ws + 17424384);                //    647,168 B
    double* cur2    = (double*)(ws + 18071552);             //    524,288 B
    double* cur_fix = (double*)(ws + 18595840);             // 33,554,432 B
    // spk_bits aliases the head of cur_fix: dead after k_cur2, cur_fix born at k_fixA
    unsigned long long* spk_bits = (unsigned long long*)(ws + 18595840); // 524,288 B
    int*    nh      = (int*)(ws + 52150272);                //        512 B
    int*    hlist   = (int*)(ws + 52150784);                //     65,536 B
    // total ws use: 52,216,320 B

    k_split<<<128, 256, 0, stream>>>(W1, W1h, W1l, nh);
    k_gemm<<<512, 256, 0, stream>>>(x, W1h, W1l, cur1);
    k_lif1<<<64, 256, 0, stream>>>(cur1, b1, spk_bits, nh, hlist);
    k_cur2<<<128, 256, 0, stream>>>(spk_bits, W2, b2, cur2);
    k_fixA<<<2048, 256, 0, stream>>>(x, W1, nh, hlist, cur_fix);
    k_fixB<<<128, 128, 0, stream>>>(cur1, cur_fix, b1, W2, nh, hlist, cur2);
    k_lif2<<<1, 256, 0, stream>>>(cur2, out);
}

// Round 2
// 778.884 us; speedup vs baseline: 1.0740x; 1.0136x over previous
//
#include <hip/hip_runtime.h>
#include <hip/hip_bf16.h>

#define T_STEPS 256
#define B_SZ    128
#define F_SZ    2500
#define F4      625        // F_SZ / 4
#define NSTEP   79         // ceil(2500/32)
#define H_SZ    128
#define O_SZ    2
#define FLAG_WINDOW 8e-5   // |mem-1| < window => fp64 recheck (split-bf16 cur1 err sigma ~9e-6, mem ~2e-5)
#define CHUNK   12         // flagged W1 rows staged in LDS per pass (120 KB)

typedef unsigned short U16;
typedef short  s16x8 __attribute__((ext_vector_type(8)));
typedef U16    u16x8 __attribute__((ext_vector_type(8)));
typedef float  f32x4 __attribute__((ext_vector_type(4)));

__device__ __forceinline__ U16 bf16c(float f) {   // RNE via HW cvt (compiler fuses pairs to v_cvt_pk_bf16_f32)
    union { __hip_bfloat16 h; U16 u; } cv;
    cv.h = __float2bfloat16(f);
    return cv.u;
}
__device__ __forceinline__ float bf2f(U16 u) { return __uint_as_float((unsigned)u << 16); }

__device__ __forceinline__ void gld16(const void* g, void* l) {
    __builtin_amdgcn_global_load_lds((const __attribute__((address_space(1))) void*)g,
                                     (__attribute__((address_space(3))) void*)l, 16, 0, 0);
}

// ---------------- K1: build pre-swizzled bf16 hi/lo weight image; zero flag counts ----------------
// Wimg[p][kt] is the exact 8KB LDS B-tile image: 64 rows (h = p*64+r) x 8 16B units;
// storage unit u holds logical unit lu = u ^ (r&7); lu<4 => hi k-subchunk lu, lu>=4 => lo subchunk lu-4.
// k_gemm DMA-copies it linearly (global_load_lds) and reads with the same XOR => conflict-free.
__global__ __launch_bounds__(256) void k_split(const float* __restrict__ W1,
                                               U16* __restrict__ Wimg,
                                               int* __restrict__ nh) {
    const int bid = blockIdx.x;                 // p*NSTEP + kt, 158 blocks
    const int p = bid / NSTEP, kt = bid - p * NSTEP;
    if (bid == 0 && threadIdx.x < B_SZ) nh[threadIdx.x] = 0;
    U16* img = Wimg + ((size_t)bid << 12);      // 4096 u16 per tile
    #pragma unroll
    for (int c = 0; c < 2; ++c) {
        const int v  = c * 256 + threadIdx.x;   // 0..511 : 16B unit index
        const int r  = v >> 3, u = v & 7;
        const int lu = u ^ (r & 7);
        const int kb = kt * 32 + (lu & 3) * 8;
        const int h  = p * 64 + r;
        u16x8 o;
        #pragma unroll
        for (int e = 0; e < 8; ++e) {
            const int k = kb + e;
            const float w = (k < F_SZ) ? W1[(size_t)h * F_SZ + k] : 0.f;
            const U16 hi = bf16c(w);
            o[e] = (lu < 4) ? hi : bf16c(w - bf2f(hi));
        }
        *(u16x8*)(img + (size_t)v * 8) = o;
    }
}

// ---------------- K2: cur1 partial[t][b][h] = x[b][t][kslice] . W1[h][kslice] via bf16 split MFMA ----------------
// acc += hh + hl + lh + ll on mfma_f32_16x16x32_bf16. Tile 128(b) x 64(h), BK=32.
// Grid 1024 = t x h-half x k-half; 48 KB LDS -> 3 blocks/CU (12 waves/CU). XCD swizzle
// co-locates each t's 4 blocks on one XCD for x-row L2 reuse. B staged by global_load_lds
// from the pre-swizzled image (no VALU, no ds_write); A reg-staged with HW bf16 cvt.
__global__ __launch_bounds__(256, 3) void k_gemm(const float* __restrict__ x,
                                                 const U16* __restrict__ Wimg,
                                                 float* __restrict__ cur1) {
    __shared__ __align__(16) U16 Alds[2][128 * 64];   // 2 x 16 KB
    __shared__ __align__(16) U16 Blds[2][64 * 64];    // 2 x  8 KB

    const int g   = blockIdx.x;
    const int wg  = (g & 7) * 128 + (g >> 3);  // bijective: same-t quartet -> same XCD
    const int t   = wg >> 2;
    const int p   = (wg >> 1) & 1;             // h-half
    const int kh  = wg & 1;                    // k-half
    const int kt0 = kh ? 40 : 0;
    const int nst = kh ? 39 : 40;

    const int tid = threadIdx.x;

    // ---- A staging map: thread -> (row ra, 16 k starting at kq) ----
    const int ra   = tid >> 1;                 // b-row 0..127
    const int kq   = (tid & 1) << 4;           // 0 | 16
    const int au0  = (tid & 1) << 1;           // logical hi units au0, au0+1
    const int aswz = ra & 7;
    const float* xrow = x + ((size_t)ra * T_STEPS + t) * F_SZ;

    // ---- B staging: linear 8KB DMA from image ----
    const char* wbase = (const char*)Wimg + ((size_t)p * NSTEP << 13);

    // ---- wave / fragment map ----
    const int lane = tid & 63, wid = tid >> 6;
    const int wm0 = (wid >> 1) << 6;           // 0 | 64  (b)
    const int wn0 = (wid & 1) << 5;            // 0 | 32  (h)
    const int lr = lane & 15, lg = lane >> 4;

    f32x4 acc[4][2];
    #pragma unroll
    for (int i = 0; i < 4; ++i)
        #pragma unroll
        for (int j = 0; j < 2; ++j) {
            acc[i][j][0] = 0.f; acc[i][j][1] = 0.f; acc[i][j][2] = 0.f; acc[i][j][3] = 0.f;
        }

    float4 xr[4];

    auto loadX = [&](int kt) {
        const int kk = kt * 32;
        #pragma unroll
        for (int c = 0; c < 4; ++c) {
            const int k = kk + kq + c * 4;
            xr[c] = (k < F_SZ) ? *(const float4*)(xrow + k) : make_float4(0.f, 0.f, 0.f, 0.f);
        }
    };
    auto loadB = [&](int kt, int bb) {         // DMA 8KB tile -> Blds[bb], linear
        const char* src = wbase + ((size_t)kt << 13) + (tid << 4);
        char* dst = (char*)Blds[bb] + (tid << 4);
        gld16(src, dst);
        gld16(src + 4096, dst + 4096);
    };
    auto stageA = [&](int bb) {
        U16* Ab = Alds[bb];
        #pragma unroll
        for (int pq = 0; pq < 2; ++pq) {
            const float* f0 = (const float*)&xr[pq * 2];
            const float* f1 = (const float*)&xr[pq * 2 + 1];
            u16x8 vh, vl;
            #pragma unroll
            for (int j = 0; j < 4; ++j) {
                const U16 h0v = bf16c(f0[j]);
                const U16 h1v = bf16c(f1[j]);
                vh[j]     = h0v;
                vh[4 + j] = h1v;
                vl[j]     = bf16c(f0[j] - bf2f(h0v));
                vl[4 + j] = bf16c(f1[j] - bf2f(h1v));
            }
            *(u16x8*)(Ab + ra * 64 + (((au0 + pq) ^ aswz) << 3))     = vh;
            *(u16x8*)(Ab + ra * 64 + (((au0 + pq + 4) ^ aswz) << 3)) = vl;
        }
    };

    // prologue: fill buffer 0 with tile kt0
    loadB(kt0, 0);
    loadX(kt0);
    stageA(0);

    int bb = 0;
    #pragma unroll 1
    for (int s = 0; s < nst; ++s) {
        __syncthreads();                       // buf bb ready (DMA+writes drained); bb^1 free
        const bool more = (s + 1 < nst);
        if (more) { loadB(kt0 + s + 1, bb ^ 1); loadX(kt0 + s + 1); }  // in flight under MFMAs

        const U16* Ab = Alds[bb];
        const U16* Bb = Blds[bb];
        s16x8 ah[4], al[4], bh[2], bl[2];
        #pragma unroll
        for (int fi = 0; fi < 4; ++fi) {
            const int m = wm0 + fi * 16 + lr;
            const int msw = m & 7;
            ah[fi] = *(const s16x8*)(Ab + m * 64 + ((lg ^ msw) << 3));
            al[fi] = *(const s16x8*)(Ab + m * 64 + (((lg + 4) ^ msw) << 3));
        }
        #pragma unroll
        for (int fj = 0; fj < 2; ++fj) {
            const int n = wn0 + fj * 16 + lr;
            const int nsw = n & 7;
            bh[fj] = *(const s16x8*)(Bb + n * 64 + ((lg ^ nsw) << 3));
            bl[fj] = *(const s16x8*)(Bb + n * 64 + (((lg + 4) ^ nsw) << 3));
        }
        #pragma unroll
        for (int fi = 0; fi < 4; ++fi)
            #pragma unroll
            for (int fj = 0; fj < 2; ++fj) {
                acc[fi][fj] = __builtin_amdgcn_mfma_f32_16x16x32_bf16(ah[fi], bh[fj], acc[fi][fj], 0, 0, 0);
                acc[fi][fj] = __builtin_amdgcn_mfma_f32_16x16x32_bf16(ah[fi], bl[fj], acc[fi][fj], 0, 0, 0);
                acc[fi][fj] = __builtin_amdgcn_mfma_f32_16x16x32_bf16(al[fi], bh[fj], acc[fi][fj], 0, 0, 0);
                acc[fi][fj] = __builtin_amdgcn_mfma_f32_16x16x32_bf16(al[fi], bl[fj], acc[fi][fj], 0, 0, 0);
            }

        if (more) stageA(bb ^ 1);              // next A tile into the other buffer
        bb ^= 1;
    }

    // epilogue: C/D layout col=lane&15, row=(lane>>4)*4+reg
    float* outp = cur1 + (size_t)kh * 4194304;
    #pragma unroll
    for (int fi = 0; fi < 4; ++fi)
        #pragma unroll
        for (int fj = 0; fj < 2; ++fj) {
            const int hcol = (p << 6) + wn0 + fj * 16 + lr;
            #pragma unroll
            for (int r = 0; r < 4; ++r) {
                const int brow = wm0 + fi * 16 + lg * 4 + r;
                outp[((size_t)t * B_SZ + brow) * H_SZ + hcol] = acc[fi][fj][r];
            }
        }
}

// ---------------- K3: merge k-halves (fp32, deterministic) + LIF1 fp64 chain; spikes -> bitmasks ----------------
// Stores merged cur1 back to part0 so k_fixB's replay is bit-identical.
__global__ __launch_bounds__(256) void k_lif1(float* __restrict__ cur1,
                                              const float* __restrict__ b1,
                                              unsigned long long* __restrict__ spk_bits,
                                              int* __restrict__ nh,
                                              int* __restrict__ hlist) {
    const int idx = blockIdx.x * 256 + threadIdx.x;   // b*128+h
    const int b = idx >> 7, h = idx & 127;
    const double b1v = (double)b1[h];
    double mem = 0.0;
    bool flagged = false;
    #pragma unroll 4
    for (int t = 0; t < T_STEPS; ++t) {
        const float p0 = cur1[(size_t)t * 16384 + idx];
        const float p1 = cur1[4194304 + (size_t)t * 16384 + idx];
        const float mrg = p0 + p1;                    // fp32 merge, replayed exactly in k_fixB
        cur1[(size_t)t * 16384 + idx] = mrg;
        const double cur = (double)mrg + b1v;
        const double rst = (mem > 1.0) ? 1.0 : 0.0;
        mem = fma(0.9, mem, cur) - rst;               // EXACT form replicated in k_fixB
        const bool spk = (mem > 1.0);
        const unsigned long long m = __ballot(spk);
        if ((threadIdx.x & 63) == 0)
            spk_bits[((size_t)t * B_SZ + b) * 2 + ((h >> 6) & 1)] = m;
        if (!flagged && fabs(mem - 1.0) < FLAG_WINDOW) {
            flagged = true;
            int s = atomicAdd(&nh[b], 1);             // s < 128 structurally
            hlist[b * 128 + s] = h;
        }
    }
}

// ---------------- K4: cur2[t][b][o] = sum_{h set} W2[o][h] + b2[o] (fp64, from bitmasks) ----------------
__global__ __launch_bounds__(256) void k_cur2(const unsigned long long* __restrict__ bits,
                                              const float* __restrict__ W2,
                                              const float* __restrict__ b2,
                                              double* __restrict__ cur2) {
    __shared__ float w2s[256];
    w2s[threadIdx.x] = W2[threadIdx.x];
    __syncthreads();
    const int pair = blockIdx.x * 256 + threadIdx.x;  // t*128+b, grid 128 blocks
    unsigned long long m0 = bits[(size_t)pair * 2];
    unsigned long long m1 = bits[(size_t)pair * 2 + 1];
    double v0 = (double)b2[0], v1 = (double)b2[1];
    while (m0) {
        const int i = __ffsll((long long)m0) - 1; m0 &= m0 - 1;
        v0 += (double)w2s[i]; v1 += (double)w2s[128 + i];
    }
    while (m1) {
        const int i = __ffsll((long long)m1) - 1; m1 &= m1 - 1;
        v0 += (double)w2s[64 + i]; v1 += (double)w2s[192 + i];
    }
    cur2[(size_t)pair * 2]     = v0;
    cur2[(size_t)pair * 2 + 1] = v1;
}

// ---------------- K5a: exact fp64 dots for flagged neurons ----------------
__global__ __launch_bounds__(256) void k_fixA(const float* __restrict__ x,
                                              const float* __restrict__ W1,
                                              const int* __restrict__ nh,
                                              const int* __restrict__ hlist,
                                              double* __restrict__ cur_fix) {
    const int b   = blockIdx.x >> 4;
    const int tch = blockIdx.x & 15;
    const int n   = nh[b];
    if (n == 0) return;

    __shared__ float w1s[CHUNK * F_SZ];   // 120 KB
    const int tid  = threadIdx.x;
    const int wv   = tid >> 6;
    const int lane = tid & 63;

    for (int c0 = 0; c0 < n; c0 += CHUNK) {
        const int nc = (n - c0 < CHUNK) ? (n - c0) : CHUNK;
        __syncthreads();
        for (int r = 0; r < nc; ++r) {
            const int h = hlist[b * 128 + c0 + r];
            const float4* src = (const float4*)W1 + (size_t)h * F4;
            float4* dst = (float4*)(w1s + r * F_SZ);
            for (int c = tid; c < F4; c += 256) dst[c] = src[c];
        }
        __syncthreads();

        #pragma unroll 1
        for (int tt = 0; tt < 4; ++tt) {
            const int t = tch * 16 + wv * 4 + tt;
            float4 xv[10];
            const float4* xb = (const float4*)x + ((size_t)b * T_STEPS + t) * F4;
            #pragma unroll
            for (int j = 0; j < 10; ++j) {
                const int c = lane + 64 * j;
                xv[j] = (c < F4) ? xb[c] : make_float4(0.f, 0.f, 0.f, 0.f);
            }
            for (int s = 0; s < nc; ++s) {
                const float* wr = w1s + s * F_SZ;
                double p = 0.0;
                #pragma unroll
                for (int j = 0; j < 10; ++j) {
                    const int c = lane + 64 * j;
                    if (c < F4) {
                        const float4 w4 = *(const float4*)(wr + c * 4);
                        p = fma((double)xv[j].x, (double)w4.x, p);
                        p = fma((double)xv[j].y, (double)w4.y, p);
                        p = fma((double)xv[j].z, (double)w4.z, p);
                        p = fma((double)xv[j].w, (double)w4.w, p);
                    }
                }
                #pragma unroll
                for (int off = 32; off >= 1; off >>= 1) p += __shfl_down(p, off);
                if (lane == 0)
                    cur_fix[((size_t)b * 128 + c0 + s) * T_STEPS + t] = p;
            }
        }
    }
}

// ---------------- K5b: rerun approx+exact chains for flags; patch cur2 where spikes differ ----------------
__global__ __launch_bounds__(128) void k_fixB(const float* __restrict__ cur1,
                                              const double* __restrict__ cur_fix,
                                              const float* __restrict__ b1,
                                              const float* __restrict__ W2,
                                              const int* __restrict__ nh,
                                              const int* __restrict__ hlist,
                                              double* __restrict__ cur2) {
    const int b = blockIdx.x;        // 128
    const int s = threadIdx.x;       // 128
    if (s >= nh[b]) return;
    const int h = hlist[b * 128 + s];
    const double b1v = (double)b1[h];
    const double w0 = (double)W2[h], w1 = (double)W2[128 + h];
    double ma = 0.0, me = 0.0;
    for (int t = 0; t < T_STEPS; ++t) {
        const double ca = (double)cur1[((size_t)t * B_SZ + b) * H_SZ + h] + b1v;
        const double ce = cur_fix[((size_t)b * 128 + s) * T_STEPS + t] + b1v;
        const double ra = (ma > 1.0) ? 1.0 : 0.0;
        const double re = (me > 1.0) ? 1.0 : 0.0;
        ma = fma(0.9, ma, ca) - ra;   // bit-identical to k_lif1
        me = fma(0.9, me, ce) - re;
        const bool sa = (ma > 1.0), se = (me > 1.0);
        if (sa != se) {
            const double d = se ? 1.0 : -1.0;
            atomicAdd(&cur2[((size_t)t * B_SZ + b) * 2 + 0], d * w0);
            atomicAdd(&cur2[((size_t)t * B_SZ + b) * 2 + 1], d * w1);
        }
    }
}

// ---------------- K6: LIF2 (fp64) + fp32 outputs ----------------
__global__ __launch_bounds__(256) void k_lif2(const double* __restrict__ cur2,
                                              float* __restrict__ out) {
    const int tid = threadIdx.x;     // b*2+o
    double mem = 0.0;
    float* spk_out = out;
    float* mem_out = out + T_STEPS * B_SZ * O_SZ;
    #pragma unroll 8
    for (int t = 0; t < T_STEPS; ++t) {
        const double cur = cur2[t * 256 + tid];
        const double rst = (mem > 1.0) ? 1.0 : 0.0;
        mem = fma(0.9, mem, cur) - rst;
        spk_out[t * 256 + tid] = (mem > 1.0) ? 1.0f : 0.0f;
        mem_out[t * 256 + tid] = (float)mem;
    }
}

extern "C" void kernel_launch(void* const* d_in, const int* in_sizes, int n_in,
                              void* d_out, int out_size, void* d_ws, size_t ws_size,
                              hipStream_t stream) {
    const float* x  = (const float*)d_in[0];   // [128][256][2500]
    const float* W1 = (const float*)d_in[1];   // [128][2500]
    const float* b1 = (const float*)d_in[2];   // [128]
    const float* W2 = (const float*)d_in[3];   // [2][128]
    const float* b2 = (const float*)d_in[4];   // [2]
    float* out = (float*)d_out;                // 131072 floats

    char* ws = (char*)d_ws;
    // [0, 16M)        : cur1 part0, merged in-place by k_lif1
    // [16M, 50331648) : cur_fix (33.5 MB); head 16 MB doubles as cur1 part1 (dead before k_fixA)
    // [48M, +1.25M)   : Wimg; head doubles as spk_bits (Wimg dead after k_gemm)
    float*  cur1    = (float*)ws;                           // 16,777,216 B
    double* cur_fix = (double*)(ws + 16777216);             // 33,554,432 B (head = part1)
    U16*    Wimg    = (U16*)(ws + 50331648);                //  1,294,336 B
    unsigned long long* spk_bits = (unsigned long long*)(ws + 50331648); // 524,288 B (aliases Wimg)
    double* cur2    = (double*)(ws + 51625984);             //    524,288 B
    int*    nh      = (int*)(ws + 52150272);                //        512 B
    int*    hlist   = (int*)(ws + 52150784);                //     65,536 B
    // total ws use: 52,216,320 B (same as previous round)

    k_split<<<158, 256, 0, stream>>>(W1, Wimg, nh);
    k_gemm<<<1024, 256, 0, stream>>>(x, Wimg, cur1);
    k_lif1<<<64, 256, 0, stream>>>(cur1, b1, spk_bits, nh, hlist);
    k_cur2<<<128, 256, 0, stream>>>(spk_bits, W2, b2, cur2);
    k_fixA<<<2048, 256, 0, stream>>>(x, W1, nh, hlist, cur_fix);
    k_fixB<<<128, 128, 0, stream>>>(cur1, cur_fix, b1, W2, nh, hlist, cur2);
    k_lif2<<<1, 256, 0, stream>>>(cur2, out);
}